// Round 12
// baseline (301.280 us; speedup 1.0000x reference)
//
#include <hip/hip_runtime.h>
#include <hip/hip_bf16.h>
#include <hip/hip_fp16.h>
#include <math.h>

#define D 128
#define H 4

typedef __attribute__((ext_vector_type(8))) short bf16x8;
typedef __attribute__((ext_vector_type(4))) float f32x4;

// ---------------------------------------------------------------------------
// fp32 -> bf16 split helpers
// ---------------------------------------------------------------------------
__device__ __forceinline__ unsigned short f32_to_bf16_rne(float f) {
    union { float f; unsigned u; } c; c.f = f;
    unsigned u = c.u;
    return (unsigned short)((u + 0x7FFFu + ((u >> 16) & 1u)) >> 16);
}
__device__ __forceinline__ float bf16_to_f32(unsigned short h) {
    union { unsigned u; float f; } c; c.u = ((unsigned)h) << 16;
    return c.f;
}

// split 8 fp32 -> bf16 hi/lo vectors (register form)
__device__ __forceinline__ void split8(const float4 f0, const float4 f1,
                                       bf16x8& hout, bf16x8& lout)
{
    float fa[8] = {f0.x, f0.y, f0.z, f0.w, f1.x, f1.y, f1.z, f1.w};
    union { bf16x8 v; unsigned short s[8]; } hv, lv;
#pragma unroll
    for (int j = 0; j < 8; ++j) {
        unsigned short hh = f32_to_bf16_rne(fa[j]);
        hv.s[j] = hh;
        lv.s[j] = f32_to_bf16_rne(fa[j] - bf16_to_f32(hh));
    }
    hout = hv.v;
    lout = lv.v;
}

// split 8 fp32 -> hi/lo, store to LDS
__device__ __forceinline__ void split_store(const float4 f0, const float4 f1,
                                            unsigned short* dh, unsigned short* dl)
{
    bf16x8 h, l;
    split8(f0, f1, h, l);
    *(bf16x8*)dh = h;
    *(bf16x8*)dl = l;
}

// ---------------------------------------------------------------------------
// Split the four 128x128 weight matrices into one packed hi/lo pair.
// HEAD-MAJOR PERMUTATION: feature c -> p(c) = (c&3)*32 + (c>>2).
// Wq/Wk/Wv: permute OUTPUT rows; Wo: permute COLUMNS (k-dim).
// ---------------------------------------------------------------------------
__global__ __launch_bounds__(256) void convert_w(
    const float* __restrict__ Wq, const float* __restrict__ Wk,
    const float* __restrict__ Wv, const float* __restrict__ Wo,
    unsigned short* __restrict__ wh, unsigned short* __restrict__ wl)
{
    int i = blockIdx.x * blockDim.x + threadIdx.x;
    if (i >= D * D) return;
    int r = i >> 7;      // output feature (row of W)
    int c = i & 127;     // k index (col of W)
    int pr = ((r & 3) << 5) | (r >> 2);   // permuted row
    int pc = ((c & 3) << 5) | (c >> 2);   // permuted col
    const float* Ws[4] = {Wq, Wk, Wv, Wo};
#pragma unroll
    for (int m = 0; m < 4; ++m) {
        float f = Ws[m][i];
        unsigned short h = f32_to_bf16_rne(f);
        unsigned short l = f32_to_bf16_rne(f - bf16_to_f32(h));
        int dst = (m < 3) ? (pr * D + c) : (r * D + pc);
        wh[m * D * D + dst] = h;
        wl[m * D * D + dst] = l;
    }
}

// ===========================================================================
// Persistent double-buffered split-precision MFMA GEMM (fp32 input) — the
// round-11 measured-best QKV structure, unchanged.  510 blocks (2/CU, all
// resident), sel = bid%3, 2-phase pipeline, one barrier/iter.
// ===========================================================================
#define RT 64   // rows per tile

__global__ __launch_bounds__(512) void gemm_pipe(
    const float* __restrict__ A,
    const unsigned short* __restrict__ whAll, const unsigned short* __restrict__ wlAll,
    const float* __restrict__ b0, const float* __restrict__ b1,
    const float* __restrict__ b2,
    void* __restrict__ o0, void* __restrict__ o1, void* __restrict__ o2,
    float scale0, int n, int wbase, int halfmask, int permBias,
    int nsel, int gx)
{
    __shared__ unsigned short Ah[2][RT * 128];   // 32 KB
    __shared__ unsigned short Al[2][RT * 128];   // 32 KB

    const int sel    = blockIdx.x % nsel;
    const int tile0  = blockIdx.x / nsel;
    const int tstride = gridDim.x / nsel;

    const unsigned short* wh = whAll + (size_t)(wbase + sel) * D * D;
    const unsigned short* wl = wlAll + (size_t)(wbase + sel) * D * D;
    const float* bias = (sel == 0) ? b0 : (sel == 1 ? b1 : b2);
    void* out        = (sel == 0) ? o0 : (sel == 1 ? o1 : o2);
    const float scale = (sel == 0) ? scale0 : 1.0f;
    const bool halfOut = (halfmask >> sel) & 1;

    const int wid  = threadIdx.x >> 6;   // col strip [16*wid, 16*wid+16)
    const int lane = threadIdx.x & 63;
    const int quad = lane >> 4;
    const int l16  = lane & 15;

    // ---- B fragments in registers once (weights hot in L1/L2) ----
    const unsigned short* wrh = wh + (size_t)(wid * 16 + l16) * D + quad * 8;
    const unsigned short* wrl = wl + (size_t)(wid * 16 + l16) * D + quad * 8;
    bf16x8 bh[4], bl[4];
#pragma unroll
    for (int kc = 0; kc < 4; ++kc) {
        bh[kc] = *(const bf16x8*)(wrh + kc * 32);
        bl[kc] = *(const bf16x8*)(wrl + kc * 32);
    }

    // ---- per-thread staging chunk geometry (2 chunks of 8 fp32 each) ----
    const int idxA = threadIdx.x;          // chunk 0
    const int idxB = threadIdx.x + 512;    // chunk 1
    const int rA = idxA >> 4, cA = idxA & 15;
    const int rB = idxB >> 4, cB = idxB & 15;
    const int dA = rA * 128 + ((cA ^ (rA & 15)) * 8);   // swizzled LDS offset
    const int dB = rB * 128 + ((cB ^ (rB & 15)) * 8);

    // ---- prologue: stage tile0 into buffer 0 ----
    {
        int rgA = tile0 * RT + rA; if (rgA > n - 1) rgA = n - 1;
        int rgB = tile0 * RT + rB; if (rgB > n - 1) rgB = n - 1;
        const float4* pA = (const float4*)(A + (size_t)rgA * D + cA * 8);
        const float4* pB = (const float4*)(A + (size_t)rgB * D + cB * 8);
        float4 a0 = pA[0], a1 = pA[1], a2 = pB[0], a3 = pB[1];
        split_store(a0, a1, &Ah[0][dA], &Al[0][dA]);
        split_store(a2, a3, &Ah[0][dB], &Al[0][dB]);
    }
    __syncthreads();

    int cur = 0;
    for (int t = tile0; t < gx; t += tstride) {
        const int tn = t + tstride;
        const bool more = (tn < gx);

        // ---- issue next tile's loads (in flight across the compute) ----
        float4 a0, a1, a2, a3;
        if (more) {
            int rgA = tn * RT + rA; if (rgA > n - 1) rgA = n - 1;
            int rgB = tn * RT + rB; if (rgB > n - 1) rgB = n - 1;
            const float4* pA = (const float4*)(A + (size_t)rgA * D + cA * 8);
            const float4* pB = (const float4*)(A + (size_t)rgB * D + cB * 8);
            a0 = pA[0]; a1 = pA[1]; a2 = pB[0]; a3 = pB[1];
        }

        // ---- compute tile t from LDS[cur] ----
        f32x4 acc[4];
#pragma unroll
        for (int rt = 0; rt < 4; ++rt) acc[rt] = (f32x4){0.f, 0.f, 0.f, 0.f};

#pragma unroll
        for (int kc = 0; kc < 4; ++kc) {
            const int cs = ((quad + 4 * kc) ^ l16) * 8;
            bf16x8 ah[4], al[4];
#pragma unroll
            for (int rt = 0; rt < 4; ++rt) {
                const int r = rt * 16 + l16;
                ah[rt] = *(const bf16x8*)&Ah[cur][r * 128 + cs];
                al[rt] = *(const bf16x8*)&Al[cur][r * 128 + cs];
            }
#pragma unroll
            for (int rt = 0; rt < 4; ++rt)
                acc[rt] = __builtin_amdgcn_mfma_f32_16x16x32_bf16(ah[rt], bh[kc], acc[rt], 0, 0, 0);
#pragma unroll
            for (int rt = 0; rt < 4; ++rt)
                acc[rt] = __builtin_amdgcn_mfma_f32_16x16x32_bf16(al[rt], bh[kc], acc[rt], 0, 0, 0);
#pragma unroll
            for (int rt = 0; rt < 4; ++rt)
                acc[rt] = __builtin_amdgcn_mfma_f32_16x16x32_bf16(ah[rt], bl[kc], acc[rt], 0, 0, 0);
        }

        // ---- epilogue: bias, scale, guarded store (overlaps loads) ----
        const int m0 = t * RT;
        const int colg = wid * 16 + l16;
        const int bidx = permBias ? (((colg & 31) << 2) | (colg >> 5)) : colg;
        const float bv = bias[bidx];
        if (halfOut) {
            __half* oph = (__half*)out;
#pragma unroll
            for (int rt = 0; rt < 4; ++rt) {
#pragma unroll
                for (int r = 0; r < 4; ++r) {
                    int rowg = m0 + rt * 16 + quad * 4 + r;
                    if (rowg < n)
                        oph[(size_t)rowg * D + colg] = __float2half(acc[rt][r] + bv);
                }
            }
        } else {
            float* opf = (float*)out;
#pragma unroll
            for (int rt = 0; rt < 4; ++rt) {
#pragma unroll
                for (int r = 0; r < 4; ++r) {
                    int rowg = m0 + rt * 16 + quad * 4 + r;
                    if (rowg < n)
                        opf[(size_t)rowg * D + colg] = (acc[rt][r] + bv) * scale;
                }
            }
        }

        // ---- write next tile into the other buffer; one barrier/iter ----
        if (more) {
            split_store(a0, a1, &Ah[cur ^ 1][dA], &Al[cur ^ 1][dA]);
            split_store(a2, a3, &Ah[cur ^ 1][dB], &Al[cur ^ 1][dB]);
        }
        __syncthreads();
        cur ^= 1;
    }
}

// ---------------------------------------------------------------------------
// row_start[i] = first edge index e with row[e] >= i  (row is sorted)
// ---------------------------------------------------------------------------
__global__ void build_row_start(const int* __restrict__ row,
                                int* __restrict__ row_start, int n, int e)
{
    int i = blockIdx.x * blockDim.x + threadIdx.x;
    if (i > n) return;
    int lo = 0, hi = e;
    while (lo < hi) {
        int mid = (lo + hi) >> 1;
        if (row[mid] < i) lo = mid + 1; else hi = mid;
    }
    row_start[i] = lo;
}

// ===========================================================================
// FUSED edge phase + O-projection, one block = 32 nodes.
// Phase 1 (edge): 4 waves x 8 nodes each, existing single-pass
//   SDDMM+softmax+SPMM (head-major permuted layout, no max-subtraction);
//   y rows parked in LDS fp32 (stride 132 pad -> 2-way banks = free).
// Phase 2 (O-proj): one barrier, then 32x128 GEMM vs Wo (cols permuted
//   by convert_w so permuted y feeds directly; output in original space).
//   A-frags read fp32 from LDS Y, split to bf16 hi/lo in regs, same
//   3-MFMA combo and per-acc order as gemm_pipe -> bit-identical numerics.
// y NEVER touches HBM (round-11 counters: O-proj y round-trip was
// ~125 MB + a launch gap).  B-frags loaded per col-strip (unroll 1) to
// cap peak VGPR.
// ===========================================================================
#define MAXDEG 64
#define NPB 32   // nodes per block
#define YLD 132  // Y row stride in floats (pad: 132%32=4 -> 2-way banks)

template<bool BIG>
__device__ __forceinline__ void edge_loop(
    int lane, int sub, int grp, int deg, int e0,
    const int* cmrow, const int* __restrict__ col,
    const float4 qa, const float4 qb,
    const __half* __restrict__ k, const __half* __restrict__ v,
    float& acc0, float& acc1, float& z)
{
    for (int e = 0; e < deg; e += 4) {
        const int ei = e + grp;                 // this lane's SDDMM edge
        int c0, c1, c2, c3, cs;
        if (!BIG) {
            const int4 cc = *(const int4*)&cmrow[e];   // staged, clamp-padded
            c0 = cc.x; c1 = cc.y; c2 = cc.z; c3 = cc.w;
            cs = cmrow[ei < deg ? ei : deg - 1];
        } else {
            int es = ei < deg ? ei : deg - 1;
            cs = col[e0 + es];
            int e1 = e + 1 < deg ? e + 1 : deg - 1;
            int e2 = e + 2 < deg ? e + 2 : deg - 1;
            int e3 = e + 3 < deg ? e + 3 : deg - 1;
            c0 = col[e0 + e];
            c1 = col[e0 + e1];
            c2 = col[e0 + e2];
            c3 = col[e0 + e3];
        }
        // v gathers (independent of the dot; overlap with k latency)
        __half2 v0 = ((const __half2*)(v + ((size_t)c0 << 7)))[lane];
        __half2 v1 = ((const __half2*)(v + ((size_t)c1 << 7)))[lane];
        __half2 v2 = ((const __half2*)(v + ((size_t)c2 << 7)))[lane];
        __half2 v3 = ((const __half2*)(v + ((size_t)c3 << 7)))[lane];
        // k gather: 8 fp16 features [sub*8, sub*8+8) of edge ei (head-pure)
        union { bf16x8 v8; __half hx[8]; } ku;
        ku.v8 = *(const bf16x8*)(k + ((size_t)cs << 7) + sub * 8);
        float p = qa.x * __half2float(ku.hx[0]) + qa.y * __half2float(ku.hx[1])
                + qa.z * __half2float(ku.hx[2]) + qa.w * __half2float(ku.hx[3])
                + qb.x * __half2float(ku.hx[4]) + qb.y * __half2float(ku.hx[5])
                + qb.z * __half2float(ku.hx[6]) + qb.w * __half2float(ku.hx[7]);
        p += __shfl_xor(p, 1);
        p += __shfl_xor(p, 2);          // lane 16j+4h now holds s(edge e+j, head h)
        float ep = (ei < deg) ? __expf(p) : 0.f;
        // broadcast this lane's head-(grp) weight for each of the 4 edges
        float a0 = __shfl(ep,      4 * grp);
        float a1 = __shfl(ep, 16 + 4 * grp);
        float a2 = __shfl(ep, 32 + 4 * grp);
        float a3 = __shfl(ep, 48 + 4 * grp);
        z += (a0 + a1) + (a2 + a3);
        acc0 += a0 * __half2float(v0.x) + a1 * __half2float(v1.x)
              + a2 * __half2float(v2.x) + a3 * __half2float(v3.x);
        acc1 += a0 * __half2float(v0.y) + a1 * __half2float(v1.y)
              + a2 * __half2float(v2.y) + a3 * __half2float(v3.y);
    }
}

__global__ __launch_bounds__(256) void edge_oproj(
    const int* __restrict__ row_start,
    const float* __restrict__ q, const __half* __restrict__ k,
    const __half* __restrict__ v, const int* __restrict__ col,
    const unsigned short* __restrict__ whAll, const unsigned short* __restrict__ wlAll,
    const float* __restrict__ bo, float* __restrict__ out, int n)
{
    __shared__ float Y[NPB * YLD];     // 16.5 KB
    __shared__ int   cm[4][MAXDEG];    // 1 KB

    const int wid  = threadIdx.x >> 6;
    const int lane = threadIdx.x & 63;
    const int quad = lane >> 4;
    const int l16  = lane & 15;
    const int base = blockIdx.x * NPB;

    // ---------------- Phase 1: edge attention, 8 nodes per wave ----------
    for (int i = 0; i < 8; ++i) {
        const int lr   = wid * 8 + i;
        const int node = base + lr;
        float acc0 = 0.f, acc1 = 0.f, z = 0.f;
        if (node < n) {
            const int e0  = row_start[node];
            const int deg = row_start[node + 1] - e0;
            const float4* q4 = (const float4*)(q + (size_t)node * D) + l16 * 2;
            const float4 qa = q4[0], qb = q4[1];
            if (deg <= MAXDEG) {
                const int dl4 = (deg + 3) & ~3;
                for (int ii = lane; ii < dl4; ii += 64) {
                    int jj = ii < deg ? ii : deg - 1;
                    cm[wid][ii] = col[e0 + jj];
                }
                edge_loop<false>(lane, l16, quad, deg, e0, cm[wid], col,
                                 qa, qb, k, v, acc0, acc1, z);
            } else {
                edge_loop<true>(lane, l16, quad, deg, e0, cm[wid], col,
                                qa, qb, k, v, acc0, acc1, z);
            }
        }
        const float rz = (z > 0.f) ? 1.f / z : 0.f;
        float2 o; o.x = acc0 * rz; o.y = acc1 * rz;
        *(float2*)&Y[lr * YLD + 2 * lane] = o;    // zero rows for node>=n
    }
    __syncthreads();

    // ---------------- Phase 2: O-projection, 32x128 tile from LDS --------
    const unsigned short* wh = whAll + (size_t)3 * D * D;
    const unsigned short* wl = wlAll + (size_t)3 * D * D;

#pragma unroll 1
    for (int s = 0; s < 2; ++s) {              // two 16-col strips per wave
        const int colg = wid * 32 + s * 16 + l16;
        const unsigned short* wrh = wh + (size_t)colg * D + quad * 8;
        const unsigned short* wrl = wl + (size_t)colg * D + quad * 8;
        bf16x8 bh[4], bl[4];
#pragma unroll
        for (int kc = 0; kc < 4; ++kc) {
            bh[kc] = *(const bf16x8*)(wrh + kc * 32);
            bl[kc] = *(const bf16x8*)(wrl + kc * 32);
        }

        f32x4 a0 = (f32x4){0.f, 0.f, 0.f, 0.f};
        f32x4 a1 = (f32x4){0.f, 0.f, 0.f, 0.f};
#pragma unroll
        for (int kc = 0; kc < 4; ++kc) {
            const int kb = quad * 8 + kc * 32;
            const float4 f00 = *(const float4*)&Y[(l16)      * YLD + kb];
            const float4 f01 = *(const float4*)&Y[(l16)      * YLD + kb + 4];
            const float4 f10 = *(const float4*)&Y[(16 + l16) * YLD + kb];
            const float4 f11 = *(const float4*)&Y[(16 + l16) * YLD + kb + 4];
            bf16x8 ah0, al0, ah1, al1;
            split8(f00, f01, ah0, al0);
            split8(f10, f11, ah1, al1);
            // same per-acc order as gemm_pipe: ah*bh, al*bh, ah*bl
            a0 = __builtin_amdgcn_mfma_f32_16x16x32_bf16(ah0, bh[kc], a0, 0, 0, 0);
            a1 = __builtin_amdgcn_mfma_f32_16x16x32_bf16(ah1, bh[kc], a1, 0, 0, 0);
            a0 = __builtin_amdgcn_mfma_f32_16x16x32_bf16(al0, bh[kc], a0, 0, 0, 0);
            a1 = __builtin_amdgcn_mfma_f32_16x16x32_bf16(al1, bh[kc], a1, 0, 0, 0);
            a0 = __builtin_amdgcn_mfma_f32_16x16x32_bf16(ah0, bl[kc], a0, 0, 0, 0);
            a1 = __builtin_amdgcn_mfma_f32_16x16x32_bf16(ah1, bl[kc], a1, 0, 0, 0);
        }

        const float bv = bo[colg];    // output in original feature space
#pragma unroll
        for (int r = 0; r < 4; ++r) {
            int rowg = base + quad * 4 + r;
            if (rowg < n)
                out[(size_t)rowg * D + colg] = a0[r] + bv;
        }
#pragma unroll
        for (int r = 0; r < 4; ++r) {
            int rowg = base + 16 + quad * 4 + r;
            if (rowg < n)
                out[(size_t)rowg * D + colg] = a1[r] + bv;
        }
    }
}

// ---------------------------------------------------------------------------
extern "C" void kernel_launch(void* const* d_in, const int* in_sizes, int n_in,
                              void* d_out, int out_size, void* d_ws, size_t ws_size,
                              hipStream_t stream)
{
    const float* x   = (const float*)d_in[0];
    const int*   row = (const int*)  d_in[1];
    const int*   col = (const int*)  d_in[2];
    const float* Wq  = (const float*)d_in[3];
    const float* bq  = (const float*)d_in[4];
    const float* Wk  = (const float*)d_in[5];
    const float* bk  = (const float*)d_in[6];
    const float* Wv  = (const float*)d_in[7];
    const float* bv  = (const float*)d_in[8];
    const float* Wo  = (const float*)d_in[9];
    const float* bo  = (const float*)d_in[10];
    float* out = (float*)d_out;

    const int n = in_sizes[0] / D;   // 100000
    const int e = in_sizes[1];       // 800000
    const size_t ND = (size_t)n * D;

    // Workspace (floats as unit):
    //   [0,    ND)   q  fp32 (permuted feature space)
    //   [ND,  1.5ND) kh fp16 (permuted)
    //   [1.5ND,2ND)  vh fp16 (permuted)
    //   [2ND, ...)   wh, wl (4*D*D shorts each), row_start
    float* ws = (float*)d_ws;
    float*  q  = ws;
    __half* kh = (__half*)(ws + ND);
    __half* vh = kh + ND;
    unsigned short* wh = (unsigned short*)(ws + 2 * ND);
    unsigned short* wl = wh + 4 * D * D;
    int* row_start = (int*)(wl + 4 * D * D);

    const int gx = (n + RT - 1) / RT;    // 1563

    convert_w<<<(D * D + 255) / 256, 256, 0, stream>>>(Wq, Wk, Wv, Wo, wh, wl);

    // fused QKV from fp32 x, persistent pipelined, sel = bid%3 (round-11
    // measured best: 510 blocks = 2/CU all resident, no straggler round)
    gemm_pipe<<<510, 512, 0, stream>>>(
        x, wh, wl, bq, bk, bv,
        (void*)q, (void*)kh, (void*)vh, 0.5f, n, 0, /*halfmask=*/6, /*permBias=*/1,
        /*nsel=*/3, gx);

    build_row_start<<<(n + 1 + 255) / 256, 256, 0, stream>>>(row, row_start, n, e);

    // fused edge attention + O-projection: y lives in LDS, never in HBM
    edge_oproj<<<(n + NPB - 1) / NPB, 256, 0, stream>>>(
        row_start, q, kh, vh, col, wh, wl, bo, out, n);
}

// Round 13
// 261.058 us; speedup vs baseline: 1.1541x; 1.1541x over previous
//
#include <hip/hip_runtime.h>
#include <hip/hip_bf16.h>
#include <hip/hip_fp16.h>
#include <math.h>

#define D 128
#define H 4

typedef __attribute__((ext_vector_type(8))) short bf16x8;
typedef __attribute__((ext_vector_type(4))) float f32x4;

// ---------------------------------------------------------------------------
// fp32 -> bf16 split helpers
// ---------------------------------------------------------------------------
__device__ __forceinline__ unsigned short f32_to_bf16_rne(float f) {
    union { float f; unsigned u; } c; c.f = f;
    unsigned u = c.u;
    return (unsigned short)((u + 0x7FFFu + ((u >> 16) & 1u)) >> 16);
}
__device__ __forceinline__ float bf16_to_f32(unsigned short h) {
    union { unsigned u; float f; } c; c.u = ((unsigned)h) << 16;
    return c.f;
}

// split 8 fp32 -> hi/lo, store to LDS
__device__ __forceinline__ void split_store(const float4 f0, const float4 f1,
                                            unsigned short* dh, unsigned short* dl)
{
    float fa[8] = {f0.x, f0.y, f0.z, f0.w, f1.x, f1.y, f1.z, f1.w};
    union { bf16x8 v; unsigned short s[8]; } hv, lv;
#pragma unroll
    for (int j = 0; j < 8; ++j) {
        unsigned short hh = f32_to_bf16_rne(fa[j]);
        hv.s[j] = hh;
        lv.s[j] = f32_to_bf16_rne(fa[j] - bf16_to_f32(hh));
    }
    *(bf16x8*)dh = hv.v;
    *(bf16x8*)dl = lv.v;
}

// ---------------------------------------------------------------------------
// Split the four 128x128 weight matrices into one packed hi/lo pair.
// HEAD-MAJOR PERMUTATION: feature c -> p(c) = (c&3)*32 + (c>>2).
// Wq/Wk/Wv: permute OUTPUT rows; Wo: permute COLUMNS (k-dim).
// ---------------------------------------------------------------------------
__global__ __launch_bounds__(256) void convert_w(
    const float* __restrict__ Wq, const float* __restrict__ Wk,
    const float* __restrict__ Wv, const float* __restrict__ Wo,
    unsigned short* __restrict__ wh, unsigned short* __restrict__ wl)
{
    int i = blockIdx.x * blockDim.x + threadIdx.x;
    if (i >= D * D) return;
    int r = i >> 7;      // output feature (row of W)
    int c = i & 127;     // k index (col of W)
    int pr = ((r & 3) << 5) | (r >> 2);   // permuted row
    int pc = ((c & 3) << 5) | (c >> 2);   // permuted col
    const float* Ws[4] = {Wq, Wk, Wv, Wo};
#pragma unroll
    for (int m = 0; m < 4; ++m) {
        float f = Ws[m][i];
        unsigned short h = f32_to_bf16_rne(f);
        unsigned short l = f32_to_bf16_rne(f - bf16_to_f32(h));
        int dst = (m < 3) ? (pr * D + c) : (r * D + pc);
        wh[m * D * D + dst] = h;
        wl[m * D * D + dst] = l;
    }
}

// ===========================================================================
// Persistent double-buffered split-precision MFMA GEMM (fp32 input) — the
// round-11 measured-best structure, unchanged.  510 blocks (2/CU, all
// resident), sel = bid%nsel, 2-phase pipeline, one barrier/iter.
// ===========================================================================
#define RT 64   // rows per tile

__global__ __launch_bounds__(512) void gemm_pipe(
    const float* __restrict__ A,
    const unsigned short* __restrict__ whAll, const unsigned short* __restrict__ wlAll,
    const float* __restrict__ b0, const float* __restrict__ b1,
    const float* __restrict__ b2,
    void* __restrict__ o0, void* __restrict__ o1, void* __restrict__ o2,
    float scale0, int n, int wbase, int halfmask, int permBias,
    int nsel, int gx)
{
    __shared__ unsigned short Ah[2][RT * 128];   // 32 KB
    __shared__ unsigned short Al[2][RT * 128];   // 32 KB

    const int sel    = blockIdx.x % nsel;
    const int tile0  = blockIdx.x / nsel;
    const int tstride = gridDim.x / nsel;

    const unsigned short* wh = whAll + (size_t)(wbase + sel) * D * D;
    const unsigned short* wl = wlAll + (size_t)(wbase + sel) * D * D;
    const float* bias = (sel == 0) ? b0 : (sel == 1 ? b1 : b2);
    void* out        = (sel == 0) ? o0 : (sel == 1 ? o1 : o2);
    const float scale = (sel == 0) ? scale0 : 1.0f;
    const bool halfOut = (halfmask >> sel) & 1;

    const int wid  = threadIdx.x >> 6;   // col strip [16*wid, 16*wid+16)
    const int lane = threadIdx.x & 63;
    const int quad = lane >> 4;
    const int l16  = lane & 15;

    // ---- B fragments in registers once (weights hot in L1/L2) ----
    const unsigned short* wrh = wh + (size_t)(wid * 16 + l16) * D + quad * 8;
    const unsigned short* wrl = wl + (size_t)(wid * 16 + l16) * D + quad * 8;
    bf16x8 bh[4], bl[4];
#pragma unroll
    for (int kc = 0; kc < 4; ++kc) {
        bh[kc] = *(const bf16x8*)(wrh + kc * 32);
        bl[kc] = *(const bf16x8*)(wrl + kc * 32);
    }

    // ---- per-thread staging chunk geometry (2 chunks of 8 fp32 each) ----
    const int idxA = threadIdx.x;          // chunk 0
    const int idxB = threadIdx.x + 512;    // chunk 1
    const int rA = idxA >> 4, cA = idxA & 15;
    const int rB = idxB >> 4, cB = idxB & 15;
    const int dA = rA * 128 + ((cA ^ (rA & 15)) * 8);   // swizzled LDS offset
    const int dB = rB * 128 + ((cB ^ (rB & 15)) * 8);

    // ---- prologue: stage tile0 into buffer 0 ----
    {
        int rgA = tile0 * RT + rA; if (rgA > n - 1) rgA = n - 1;
        int rgB = tile0 * RT + rB; if (rgB > n - 1) rgB = n - 1;
        const float4* pA = (const float4*)(A + (size_t)rgA * D + cA * 8);
        const float4* pB = (const float4*)(A + (size_t)rgB * D + cB * 8);
        float4 a0 = pA[0], a1 = pA[1], a2 = pB[0], a3 = pB[1];
        split_store(a0, a1, &Ah[0][dA], &Al[0][dA]);
        split_store(a2, a3, &Ah[0][dB], &Al[0][dB]);
    }
    __syncthreads();

    int cur = 0;
    for (int t = tile0; t < gx; t += tstride) {
        const int tn = t + tstride;
        const bool more = (tn < gx);

        // ---- issue next tile's loads (in flight across the compute) ----
        float4 a0, a1, a2, a3;
        if (more) {
            int rgA = tn * RT + rA; if (rgA > n - 1) rgA = n - 1;
            int rgB = tn * RT + rB; if (rgB > n - 1) rgB = n - 1;
            const float4* pA = (const float4*)(A + (size_t)rgA * D + cA * 8);
            const float4* pB = (const float4*)(A + (size_t)rgB * D + cB * 8);
            a0 = pA[0]; a1 = pA[1]; a2 = pB[0]; a3 = pB[1];
        }

        // ---- compute tile t from LDS[cur] ----
        f32x4 acc[4];
#pragma unroll
        for (int rt = 0; rt < 4; ++rt) acc[rt] = (f32x4){0.f, 0.f, 0.f, 0.f};

#pragma unroll
        for (int kc = 0; kc < 4; ++kc) {
            const int cs = ((quad + 4 * kc) ^ l16) * 8;
            bf16x8 ah[4], al[4];
#pragma unroll
            for (int rt = 0; rt < 4; ++rt) {
                const int r = rt * 16 + l16;
                ah[rt] = *(const bf16x8*)&Ah[cur][r * 128 + cs];
                al[rt] = *(const bf16x8*)&Al[cur][r * 128 + cs];
            }
#pragma unroll
            for (int rt = 0; rt < 4; ++rt)
                acc[rt] = __builtin_amdgcn_mfma_f32_16x16x32_bf16(ah[rt], bh[kc], acc[rt], 0, 0, 0);
#pragma unroll
            for (int rt = 0; rt < 4; ++rt)
                acc[rt] = __builtin_amdgcn_mfma_f32_16x16x32_bf16(al[rt], bh[kc], acc[rt], 0, 0, 0);
#pragma unroll
            for (int rt = 0; rt < 4; ++rt)
                acc[rt] = __builtin_amdgcn_mfma_f32_16x16x32_bf16(ah[rt], bl[kc], acc[rt], 0, 0, 0);
        }

        // ---- epilogue: bias, scale, guarded store (overlaps loads) ----
        const int m0 = t * RT;
        const int colg = wid * 16 + l16;
        const int bidx = permBias ? (((colg & 31) << 2) | (colg >> 5)) : colg;
        const float bv = bias[bidx];
        if (halfOut) {
            __half* oph = (__half*)out;
#pragma unroll
            for (int rt = 0; rt < 4; ++rt) {
#pragma unroll
                for (int r = 0; r < 4; ++r) {
                    int rowg = m0 + rt * 16 + quad * 4 + r;
                    if (rowg < n)
                        oph[(size_t)rowg * D + colg] = __float2half(acc[rt][r] + bv);
                }
            }
        } else {
            float* opf = (float*)out;
#pragma unroll
            for (int rt = 0; rt < 4; ++rt) {
#pragma unroll
                for (int r = 0; r < 4; ++r) {
                    int rowg = m0 + rt * 16 + quad * 4 + r;
                    if (rowg < n)
                        opf[(size_t)rowg * D + colg] = (acc[rt][r] + bv) * scale;
                }
            }
        }

        // ---- write next tile into the other buffer; one barrier/iter ----
        if (more) {
            split_store(a0, a1, &Ah[cur ^ 1][dA], &Al[cur ^ 1][dA]);
            split_store(a2, a3, &Ah[cur ^ 1][dB], &Al[cur ^ 1][dB]);
        }
        __syncthreads();
        cur ^= 1;
    }
}

// ---------------------------------------------------------------------------
// row_start[i] = first edge index e with row[e] >= i  (row is sorted)
// ---------------------------------------------------------------------------
__global__ void build_row_start(const int* __restrict__ row,
                                int* __restrict__ row_start, int n, int e)
{
    int i = blockIdx.x * blockDim.x + threadIdx.x;
    if (i > n) return;
    int lo = 0, hi = e;
    while (lo < hi) {
        int mid = (lo + hi) >> 1;
        if (row[mid] < i) lo = mid + 1; else hi = mid;
    }
    row_start[i] = lo;
}

// ===========================================================================
// Fused edge phase v4: single-pass SDDMM+softmax+SPMM, one WAVE per node,
// 8-EDGE passes (two 4-edge sub-passes with ALL loads issued up front:
// 2 k-gathers + 8 v-gathers in flight -> 2x MLP vs v3; compute order and
// accumulation sequence identical to v3 -> bit-identical numerics).
// HEAD-MAJOR layout; no max-subtraction; y written fp32.
// ===========================================================================
#define MAXDEG 64
#define WPB 4

// one 4-edge compute sub-pass (loads already in registers)
__device__ __forceinline__ void edge_compute4(
    int lane, int grp, int ei, int deg,
    const __half2 v0, const __half2 v1, const __half2 v2, const __half2 v3,
    const bf16x8 kvec, const float4 qa, const float4 qb,
    float& acc0, float& acc1, float& z)
{
    union { bf16x8 v8; __half hx[8]; } ku; ku.v8 = kvec;
    float p = qa.x * __half2float(ku.hx[0]) + qa.y * __half2float(ku.hx[1])
            + qa.z * __half2float(ku.hx[2]) + qa.w * __half2float(ku.hx[3])
            + qb.x * __half2float(ku.hx[4]) + qb.y * __half2float(ku.hx[5])
            + qb.z * __half2float(ku.hx[6]) + qb.w * __half2float(ku.hx[7]);
    p += __shfl_xor(p, 1);
    p += __shfl_xor(p, 2);          // lane 16j+4h holds s(edge base+j, head h)
    float ep = (ei < deg) ? __expf(p) : 0.f;
    float a0 = __shfl(ep,      4 * grp);
    float a1 = __shfl(ep, 16 + 4 * grp);
    float a2 = __shfl(ep, 32 + 4 * grp);
    float a3 = __shfl(ep, 48 + 4 * grp);
    z += (a0 + a1) + (a2 + a3);
    acc0 += a0 * __half2float(v0.x) + a1 * __half2float(v1.x)
          + a2 * __half2float(v2.x) + a3 * __half2float(v3.x);
    acc1 += a0 * __half2float(v0.y) + a1 * __half2float(v1.y)
          + a2 * __half2float(v2.y) + a3 * __half2float(v3.y);
}

// rare big-degree path (unchanged 4-edge loop, col from global)
__device__ __forceinline__ void edge_loop_big(
    int lane, int sub, int grp, int deg, int e0,
    const int* __restrict__ col,
    const float4 qa, const float4 qb,
    const __half* __restrict__ k, const __half* __restrict__ v,
    float& acc0, float& acc1, float& z)
{
    for (int e = 0; e < deg; e += 4) {
        const int ei = e + grp;
        int es = ei < deg ? ei : deg - 1;
        int cs = col[e0 + es];
        int e1 = e + 1 < deg ? e + 1 : deg - 1;
        int e2 = e + 2 < deg ? e + 2 : deg - 1;
        int e3 = e + 3 < deg ? e + 3 : deg - 1;
        int c0 = col[e0 + e];
        int c1 = col[e0 + e1];
        int c2 = col[e0 + e2];
        int c3 = col[e0 + e3];
        __half2 v0 = ((const __half2*)(v + ((size_t)c0 << 7)))[lane];
        __half2 v1 = ((const __half2*)(v + ((size_t)c1 << 7)))[lane];
        __half2 v2 = ((const __half2*)(v + ((size_t)c2 << 7)))[lane];
        __half2 v3 = ((const __half2*)(v + ((size_t)c3 << 7)))[lane];
        bf16x8 kv = *(const bf16x8*)(k + ((size_t)cs << 7) + sub * 8);
        edge_compute4(lane, grp, ei, deg, v0, v1, v2, v3, kv, qa, qb,
                      acc0, acc1, z);
    }
}

__global__ __launch_bounds__(WPB * 64) void edge_attn(
    const int* __restrict__ row_start,
    const float* __restrict__ q, const __half* __restrict__ k,
    const __half* __restrict__ v, const int* __restrict__ col,
    float* __restrict__ y, int n)
{
    __shared__ int cm[WPB][MAXDEG];

    const int wid  = threadIdx.x >> 6;
    const int lane = threadIdx.x & 63;
    const int node = blockIdx.x * WPB + wid;
    if (node >= n) return;

    const int e0  = row_start[node];
    const int deg = row_start[node + 1] - e0;
    const int sub = lane & 15;   // SDDMM feature chunk
    const int grp = lane >> 4;   // SDDMM edge slot == SPMM head

    // q chunk per lane: features [sub*8, sub*8+8) — 8 fp32
    const float4* q4 = (const float4*)(q + (size_t)node * D) + sub * 2;
    const float4 qa = q4[0], qb = q4[1];

    float acc0 = 0.f, acc1 = 0.f, z = 0.f;

    if (deg <= MAXDEG) {
        // stage cols, padded to multiple of 8 with clamped index
        const int dl8 = (deg + 7) & ~7;
        for (int i = lane; i < dl8; i += 64) {
            int ii = i < deg ? i : deg - 1;
            cm[wid][i] = col[e0 + ii];
        }
        const int* cmrow = cm[wid];
        for (int e = 0; e < deg; e += 8) {
            const int eiA = e + grp;
            const int eiB = e + 4 + grp;
            // ---- issue ALL loads for both sub-passes up front ----
            const int4 ccA = *(const int4*)&cmrow[e];
            const int4 ccB = *(const int4*)&cmrow[e + 4];   // padded, safe
            const int csA = cmrow[eiA < deg ? eiA : deg - 1];
            const int csB = cmrow[eiB < deg ? eiB : deg - 1];
            __half2 vA0 = ((const __half2*)(v + ((size_t)ccA.x << 7)))[lane];
            __half2 vA1 = ((const __half2*)(v + ((size_t)ccA.y << 7)))[lane];
            __half2 vA2 = ((const __half2*)(v + ((size_t)ccA.z << 7)))[lane];
            __half2 vA3 = ((const __half2*)(v + ((size_t)ccA.w << 7)))[lane];
            __half2 vB0 = ((const __half2*)(v + ((size_t)ccB.x << 7)))[lane];
            __half2 vB1 = ((const __half2*)(v + ((size_t)ccB.y << 7)))[lane];
            __half2 vB2 = ((const __half2*)(v + ((size_t)ccB.z << 7)))[lane];
            __half2 vB3 = ((const __half2*)(v + ((size_t)ccB.w << 7)))[lane];
            bf16x8 kvA = *(const bf16x8*)(k + ((size_t)csA << 7) + sub * 8);
            bf16x8 kvB = *(const bf16x8*)(k + ((size_t)csB << 7) + sub * 8);
            // ---- sub-pass A then B: same sequential accumulation as v3 ----
            edge_compute4(lane, grp, eiA, deg, vA0, vA1, vA2, vA3, kvA,
                          qa, qb, acc0, acc1, z);
            if (e + 4 < deg)
                edge_compute4(lane, grp, eiB, deg, vB0, vB1, vB2, vB3, kvB,
                              qa, qb, acc0, acc1, z);
        }
    } else {
        edge_loop_big(lane, sub, grp, deg, e0, col, qa, qb, k, v,
                      acc0, acc1, z);
    }

    const float rz = (z > 0.f) ? 1.f / z : 0.f;   // deg==0 / underflow -> 0
    acc0 *= rz;
    acc1 *= rz;

    // ---- write y fp32 (permuted space, features 2*lane, 2*lane+1) ----
    float2 o; o.x = acc0; o.y = acc1;
    ((float2*)y)[(size_t)node * 64 + lane] = o;
}

// ---------------------------------------------------------------------------
extern "C" void kernel_launch(void* const* d_in, const int* in_sizes, int n_in,
                              void* d_out, int out_size, void* d_ws, size_t ws_size,
                              hipStream_t stream)
{
    const float* x   = (const float*)d_in[0];
    const int*   row = (const int*)  d_in[1];
    const int*   col = (const int*)  d_in[2];
    const float* Wq  = (const float*)d_in[3];
    const float* bq  = (const float*)d_in[4];
    const float* Wk  = (const float*)d_in[5];
    const float* bk  = (const float*)d_in[6];
    const float* Wv  = (const float*)d_in[7];
    const float* bv  = (const float*)d_in[8];
    const float* Wo  = (const float*)d_in[9];
    const float* bo  = (const float*)d_in[10];
    float* out = (float*)d_out;

    const int n = in_sizes[0] / D;   // 100000
    const int e = in_sizes[1];       // 800000
    const size_t ND = (size_t)n * D;

    // Workspace (floats as unit):
    //   [0,    ND)   q  fp32 (permuted feature space)
    //   [ND,  1.5ND) kh fp16 (permuted)
    //   [1.5ND,2ND)  vh fp16 (permuted)
    //   [2ND, 3ND)   y  fp32 (permuted)
    //   [3ND, ...)   wh, wl (4*D*D shorts each), row_start
    float* ws = (float*)d_ws;
    float*  q  = ws;
    __half* kh = (__half*)(ws + ND);
    __half* vh = kh + ND;
    float*  y  = ws + 2 * ND;
    unsigned short* wh = (unsigned short*)(ws + 3 * ND);
    unsigned short* wl = wh + 4 * D * D;
    int* row_start = (int*)(wl + 4 * D * D);

    const int gx = (n + RT - 1) / RT;    // 1563

    convert_w<<<(D * D + 255) / 256, 256, 0, stream>>>(Wq, Wk, Wv, Wo, wh, wl);

    // hoisted: only depends on row; removes serial bubble before edge_attn
    build_row_start<<<(n + 1 + 255) / 256, 256, 0, stream>>>(row, row_start, n, e);

    // fused QKV from fp32 x, persistent pipelined, sel = bid%3 (round-11
    // measured best: 510 blocks = 2/CU all resident, no straggler round)
    gemm_pipe<<<510, 512, 0, stream>>>(
        x, wh, wl, bq, bk, bv,
        (void*)q, (void*)kh, (void*)vh, 0.5f, n, 0, /*halfmask=*/6, /*permBias=*/1,
        /*nsel=*/3, gx);

    edge_attn<<<(n + WPB - 1) / WPB, WPB * 64, 0, stream>>>(
        row_start, q, kh, vh, col, y, n);

    // output projection from fp32 y, persistent pipelined (512 = all resident)
    gemm_pipe<<<512, 512, 0, stream>>>(
        y, wh, wl, bo, bo, bo,
        (void*)out, (void*)out, (void*)out, 1.0f, n, 3, /*halfmask=*/0, /*permBias=*/0,
        /*nsel=*/1, gx);
}

// Round 15
// 251.815 us; speedup vs baseline: 1.1964x; 1.0367x over previous
//
#include <hip/hip_runtime.h>
#include <hip/hip_bf16.h>
#include <hip/hip_fp16.h>
#include <math.h>

#define D 128
#define H 4

typedef __attribute__((ext_vector_type(8))) short bf16x8;
typedef __attribute__((ext_vector_type(4))) float f32x4;

// ---------------------------------------------------------------------------
// fp32 -> bf16 split helpers
// ---------------------------------------------------------------------------
__device__ __forceinline__ unsigned short f32_to_bf16_rne(float f) {
    union { float f; unsigned u; } c; c.f = f;
    unsigned u = c.u;
    return (unsigned short)((u + 0x7FFFu + ((u >> 16) & 1u)) >> 16);
}
__device__ __forceinline__ float bf16_to_f32(unsigned short h) {
    union { unsigned u; float f; } c; c.u = ((unsigned)h) << 16;
    return c.f;
}

// split 8 fp32 -> hi/lo, store to LDS
__device__ __forceinline__ void split_store(const float4 f0, const float4 f1,
                                            unsigned short* dh, unsigned short* dl)
{
    float fa[8] = {f0.x, f0.y, f0.z, f0.w, f1.x, f1.y, f1.z, f1.w};
    union { bf16x8 v; unsigned short s[8]; } hv, lv;
#pragma unroll
    for (int j = 0; j < 8; ++j) {
        unsigned short hh = f32_to_bf16_rne(fa[j]);
        hv.s[j] = hh;
        lv.s[j] = f32_to_bf16_rne(fa[j] - bf16_to_f32(hh));
    }
    *(bf16x8*)dh = hv.v;
    *(bf16x8*)dl = lv.v;
}

// ---------------------------------------------------------------------------
// Split the four 128x128 weight matrices into one packed hi/lo pair.
// HEAD-MAJOR PERMUTATION: feature c -> p(c) = (c&3)*32 + (c>>2).
// Wq/Wk/Wv: permute OUTPUT rows; Wo: permute COLUMNS (k-dim).
// ---------------------------------------------------------------------------
__global__ __launch_bounds__(256) void convert_w(
    const float* __restrict__ Wq, const float* __restrict__ Wk,
    const float* __restrict__ Wv, const float* __restrict__ Wo,
    unsigned short* __restrict__ wh, unsigned short* __restrict__ wl)
{
    int i = blockIdx.x * blockDim.x + threadIdx.x;
    if (i >= D * D) return;
    int r = i >> 7;      // output feature (row of W)
    int c = i & 127;     // k index (col of W)
    int pr = ((r & 3) << 5) | (r >> 2);   // permuted row
    int pc = ((c & 3) << 5) | (c >> 2);   // permuted col
    const float* Ws[4] = {Wq, Wk, Wv, Wo};
#pragma unroll
    for (int m = 0; m < 4; ++m) {
        float f = Ws[m][i];
        unsigned short h = f32_to_bf16_rne(f);
        unsigned short l = f32_to_bf16_rne(f - bf16_to_f32(h));
        int dst = (m < 3) ? (pr * D + c) : (r * D + pc);
        wh[m * D * D + dst] = h;
        wl[m * D * D + dst] = l;
    }
}

// ===========================================================================
// Persistent double-buffered split-precision MFMA GEMM — round-11 structure.
// NEW: A may be fp16 (aHalf=1): staged chunk loaded as 8 halves, cvt to
// fp32, then the IDENTICAL hi/lo split + MFMA sequence (fp16 is captured
// exactly by the split, so only A's own fp16 rounding is added).
// halfOut store now applies `scale` (needed for q fp16; k/v scale=1).
// ===========================================================================
#define RT 64   // rows per tile

__global__ __launch_bounds__(512) void gemm_pipe(
    const void* __restrict__ Avoid,
    const unsigned short* __restrict__ whAll, const unsigned short* __restrict__ wlAll,
    const float* __restrict__ b0, const float* __restrict__ b1,
    const float* __restrict__ b2,
    void* __restrict__ o0, void* __restrict__ o1, void* __restrict__ o2,
    float scale0, int n, int wbase, int halfmask, int permBias,
    int nsel, int gx, int aHalf)
{
    __shared__ unsigned short Ah[2][RT * 128];   // 32 KB
    __shared__ unsigned short Al[2][RT * 128];   // 32 KB

    const int sel    = blockIdx.x % nsel;
    const int tile0  = blockIdx.x / nsel;
    const int tstride = gridDim.x / nsel;

    const unsigned short* wh = whAll + (size_t)(wbase + sel) * D * D;
    const unsigned short* wl = wlAll + (size_t)(wbase + sel) * D * D;
    const float* bias = (sel == 0) ? b0 : (sel == 1 ? b1 : b2);
    void* out        = (sel == 0) ? o0 : (sel == 1 ? o1 : o2);
    const float scale = (sel == 0) ? scale0 : 1.0f;
    const bool halfOut = (halfmask >> sel) & 1;

    const float*  Af = (const float*)Avoid;
    const __half* Ax = (const __half*)Avoid;

    const int wid  = threadIdx.x >> 6;   // col strip [16*wid, 16*wid+16)
    const int lane = threadIdx.x & 63;
    const int quad = lane >> 4;
    const int l16  = lane & 15;

    // ---- B fragments in registers once (weights hot in L1/L2) ----
    const unsigned short* wrh = wh + (size_t)(wid * 16 + l16) * D + quad * 8;
    const unsigned short* wrl = wl + (size_t)(wid * 16 + l16) * D + quad * 8;
    bf16x8 bh[4], bl[4];
#pragma unroll
    for (int kc = 0; kc < 4; ++kc) {
        bh[kc] = *(const bf16x8*)(wrh + kc * 32);
        bl[kc] = *(const bf16x8*)(wrl + kc * 32);
    }

    // ---- per-thread staging chunk geometry (2 chunks of 8 elems each) ----
    const int idxA = threadIdx.x;          // chunk 0
    const int idxB = threadIdx.x + 512;    // chunk 1
    const int rA = idxA >> 4, cA = idxA & 15;
    const int rB = idxB >> 4, cB = idxB & 15;
    const int dA = rA * 128 + ((cA ^ (rA & 15)) * 8);   // swizzled LDS offset
    const int dB = rB * 128 + ((cB ^ (rB & 15)) * 8);

    // load one 8-elem chunk as two float4 (fp32 path or fp16-cvt path)
    auto loadA = [&](int rg, int c8, float4& f0, float4& f1) {
        if (aHalf) {
            union { bf16x8 v; __half h[8]; } u;
            u.v = *(const bf16x8*)(Ax + (size_t)rg * D + c8 * 8);
            f0.x = __half2float(u.h[0]); f0.y = __half2float(u.h[1]);
            f0.z = __half2float(u.h[2]); f0.w = __half2float(u.h[3]);
            f1.x = __half2float(u.h[4]); f1.y = __half2float(u.h[5]);
            f1.z = __half2float(u.h[6]); f1.w = __half2float(u.h[7]);
        } else {
            const float4* p = (const float4*)(Af + (size_t)rg * D + c8 * 8);
            f0 = p[0]; f1 = p[1];
        }
    };

    // ---- prologue: stage tile0 into buffer 0 ----
    {
        int rgA = tile0 * RT + rA; if (rgA > n - 1) rgA = n - 1;
        int rgB = tile0 * RT + rB; if (rgB > n - 1) rgB = n - 1;
        float4 a0, a1, a2, a3;
        loadA(rgA, cA, a0, a1);
        loadA(rgB, cB, a2, a3);
        split_store(a0, a1, &Ah[0][dA], &Al[0][dA]);
        split_store(a2, a3, &Ah[0][dB], &Al[0][dB]);
    }
    __syncthreads();

    int cur = 0;
    for (int t = tile0; t < gx; t += tstride) {
        const int tn = t + tstride;
        const bool more = (tn < gx);

        // ---- issue next tile's loads (in flight across the compute) ----
        float4 a0, a1, a2, a3;
        if (more) {
            int rgA = tn * RT + rA; if (rgA > n - 1) rgA = n - 1;
            int rgB = tn * RT + rB; if (rgB > n - 1) rgB = n - 1;
            loadA(rgA, cA, a0, a1);
            loadA(rgB, cB, a2, a3);
        }

        // ---- compute tile t from LDS[cur] ----
        f32x4 acc[4];
#pragma unroll
        for (int rt = 0; rt < 4; ++rt) acc[rt] = (f32x4){0.f, 0.f, 0.f, 0.f};

#pragma unroll
        for (int kc = 0; kc < 4; ++kc) {
            const int cs = ((quad + 4 * kc) ^ l16) * 8;
            bf16x8 ah[4], al[4];
#pragma unroll
            for (int rt = 0; rt < 4; ++rt) {
                const int r = rt * 16 + l16;
                ah[rt] = *(const bf16x8*)&Ah[cur][r * 128 + cs];
                al[rt] = *(const bf16x8*)&Al[cur][r * 128 + cs];
            }
#pragma unroll
            for (int rt = 0; rt < 4; ++rt)
                acc[rt] = __builtin_amdgcn_mfma_f32_16x16x32_bf16(ah[rt], bh[kc], acc[rt], 0, 0, 0);
#pragma unroll
            for (int rt = 0; rt < 4; ++rt)
                acc[rt] = __builtin_amdgcn_mfma_f32_16x16x32_bf16(al[rt], bh[kc], acc[rt], 0, 0, 0);
#pragma unroll
            for (int rt = 0; rt < 4; ++rt)
                acc[rt] = __builtin_amdgcn_mfma_f32_16x16x32_bf16(ah[rt], bl[kc], acc[rt], 0, 0, 0);
        }

        // ---- epilogue: bias, scale, guarded store (overlaps loads) ----
        const int m0 = t * RT;
        const int colg = wid * 16 + l16;
        const int bidx = permBias ? (((colg & 31) << 2) | (colg >> 5)) : colg;
        const float bv = bias[bidx];
        if (halfOut) {
            __half* oph = (__half*)out;
#pragma unroll
            for (int rt = 0; rt < 4; ++rt) {
#pragma unroll
                for (int r = 0; r < 4; ++r) {
                    int rowg = m0 + rt * 16 + quad * 4 + r;
                    if (rowg < n)
                        oph[(size_t)rowg * D + colg] = __float2half((acc[rt][r] + bv) * scale);
                }
            }
        } else {
            float* opf = (float*)out;
#pragma unroll
            for (int rt = 0; rt < 4; ++rt) {
#pragma unroll
                for (int r = 0; r < 4; ++r) {
                    int rowg = m0 + rt * 16 + quad * 4 + r;
                    if (rowg < n)
                        opf[(size_t)rowg * D + colg] = (acc[rt][r] + bv) * scale;
                }
            }
        }

        // ---- write next tile into the other buffer; one barrier/iter ----
        if (more) {
            split_store(a0, a1, &Ah[cur ^ 1][dA], &Al[cur ^ 1][dA]);
            split_store(a2, a3, &Ah[cur ^ 1][dB], &Al[cur ^ 1][dB]);
        }
        __syncthreads();
        cur ^= 1;
    }
}

// ---------------------------------------------------------------------------
// row_start[i] = first edge index e with row[e] >= i  (row is sorted)
// ---------------------------------------------------------------------------
__global__ void build_row_start(const int* __restrict__ row,
                                int* __restrict__ row_start, int n, int e)
{
    int i = blockIdx.x * blockDim.x + threadIdx.x;
    if (i > n) return;
    int lo = 0, hi = e;
    while (lo < hi) {
        int mid = (lo + hi) >> 1;
        if (row[mid] < i) lo = mid + 1; else hi = mid;
    }
    row_start[i] = lo;
}

// ===========================================================================
// Fused edge phase v5: single-pass SDDMM+softmax+SPMM, one WAVE per node.
// q now fp16 (halves FETCH for q); y written fp16 (halves WRITE).
// Same compute order as v3/v4 -> only q-fp16 and y-fp16 rounding added.
// ===========================================================================
#define MAXDEG 64
#define WPB 4

__device__ __forceinline__ void edge_compute4(
    int lane, int grp, int ei, int deg,
    const __half2 v0, const __half2 v1, const __half2 v2, const __half2 v3,
    const bf16x8 kvec, const float4 qa, const float4 qb,
    float& acc0, float& acc1, float& z)
{
    union { bf16x8 v8; __half hx[8]; } ku; ku.v8 = kvec;
    float p = qa.x * __half2float(ku.hx[0]) + qa.y * __half2float(ku.hx[1])
            + qa.z * __half2float(ku.hx[2]) + qa.w * __half2float(ku.hx[3])
            + qb.x * __half2float(ku.hx[4]) + qb.y * __half2float(ku.hx[5])
            + qb.z * __half2float(ku.hx[6]) + qb.w * __half2float(ku.hx[7]);
    p += __shfl_xor(p, 1);
    p += __shfl_xor(p, 2);          // lane 16j+4h holds s(edge base+j, head h)
    float ep = (ei < deg) ? __expf(p) : 0.f;
    float a0 = __shfl(ep,      4 * grp);
    float a1 = __shfl(ep, 16 + 4 * grp);
    float a2 = __shfl(ep, 32 + 4 * grp);
    float a3 = __shfl(ep, 48 + 4 * grp);
    z += (a0 + a1) + (a2 + a3);
    acc0 += a0 * __half2float(v0.x) + a1 * __half2float(v1.x)
          + a2 * __half2float(v2.x) + a3 * __half2float(v3.x);
    acc1 += a0 * __half2float(v0.y) + a1 * __half2float(v1.y)
          + a2 * __half2float(v2.y) + a3 * __half2float(v3.y);
}

__device__ __forceinline__ void edge_loop_big(
    int lane, int sub, int grp, int deg, int e0,
    const int* __restrict__ col,
    const float4 qa, const float4 qb,
    const __half* __restrict__ k, const __half* __restrict__ v,
    float& acc0, float& acc1, float& z)
{
    for (int e = 0; e < deg; e += 4) {
        const int ei = e + grp;
        int es = ei < deg ? ei : deg - 1;
        int cs = col[e0 + es];
        int e1 = e + 1 < deg ? e + 1 : deg - 1;
        int e2 = e + 2 < deg ? e + 2 : deg - 1;
        int e3 = e + 3 < deg ? e + 3 : deg - 1;
        int c0 = col[e0 + e];
        int c1 = col[e0 + e1];
        int c2 = col[e0 + e2];
        int c3 = col[e0 + e3];
        __half2 v0 = ((const __half2*)(v + ((size_t)c0 << 7)))[lane];
        __half2 v1 = ((const __half2*)(v + ((size_t)c1 << 7)))[lane];
        __half2 v2 = ((const __half2*)(v + ((size_t)c2 << 7)))[lane];
        __half2 v3 = ((const __half2*)(v + ((size_t)c3 << 7)))[lane];
        bf16x8 kv = *(const bf16x8*)(k + ((size_t)cs << 7) + sub * 8);
        edge_compute4(lane, grp, ei, deg, v0, v1, v2, v3, kv, qa, qb,
                      acc0, acc1, z);
    }
}

__global__ __launch_bounds__(WPB * 64) void edge_attn(
    const int* __restrict__ row_start,
    const __half* __restrict__ q, const __half* __restrict__ k,
    const __half* __restrict__ v, const int* __restrict__ col,
    __half* __restrict__ y, int n)
{
    __shared__ int cm[WPB][MAXDEG];

    const int wid  = threadIdx.x >> 6;
    const int lane = threadIdx.x & 63;
    const int node = blockIdx.x * WPB + wid;
    if (node >= n) return;

    const int e0  = row_start[node];
    const int deg = row_start[node + 1] - e0;
    const int sub = lane & 15;   // SDDMM feature chunk
    const int grp = lane >> 4;   // SDDMM edge slot == SPMM head

    // q chunk per lane: features [sub*8, sub*8+8) — 8 fp16 -> fp32 regs
    union { bf16x8 v8; __half hx[8]; } qu;
    qu.v8 = *(const bf16x8*)(q + (size_t)node * D + sub * 8);
    float4 qa, qb;
    qa.x = __half2float(qu.hx[0]); qa.y = __half2float(qu.hx[1]);
    qa.z = __half2float(qu.hx[2]); qa.w = __half2float(qu.hx[3]);
    qb.x = __half2float(qu.hx[4]); qb.y = __half2float(qu.hx[5]);
    qb.z = __half2float(qu.hx[6]); qb.w = __half2float(qu.hx[7]);

    float acc0 = 0.f, acc1 = 0.f, z = 0.f;

    if (deg <= MAXDEG) {
        // stage cols, padded to multiple of 8 with clamped index
        const int dl8 = (deg + 7) & ~7;
        for (int i = lane; i < dl8; i += 64) {
            int ii = i < deg ? i : deg - 1;
            cm[wid][i] = col[e0 + ii];
        }
        const int* cmrow = cm[wid];
        for (int e = 0; e < deg; e += 8) {
            const int eiA = e + grp;
            const int eiB = e + 4 + grp;
            const int4 ccA = *(const int4*)&cmrow[e];
            const int4 ccB = *(const int4*)&cmrow[e + 4];   // padded, safe
            const int csA = cmrow[eiA < deg ? eiA : deg - 1];
            const int csB = cmrow[eiB < deg ? eiB : deg - 1];
            __half2 vA0 = ((const __half2*)(v + ((size_t)ccA.x << 7)))[lane];
            __half2 vA1 = ((const __half2*)(v + ((size_t)ccA.y << 7)))[lane];
            __half2 vA2 = ((const __half2*)(v + ((size_t)ccA.z << 7)))[lane];
            __half2 vA3 = ((const __half2*)(v + ((size_t)ccA.w << 7)))[lane];
            __half2 vB0 = ((const __half2*)(v + ((size_t)ccB.x << 7)))[lane];
            __half2 vB1 = ((const __half2*)(v + ((size_t)ccB.y << 7)))[lane];
            __half2 vB2 = ((const __half2*)(v + ((size_t)ccB.z << 7)))[lane];
            __half2 vB3 = ((const __half2*)(v + ((size_t)ccB.w << 7)))[lane];
            bf16x8 kvA = *(const bf16x8*)(k + ((size_t)csA << 7) + sub * 8);
            bf16x8 kvB = *(const bf16x8*)(k + ((size_t)csB << 7) + sub * 8);
            edge_compute4(lane, grp, eiA, deg, vA0, vA1, vA2, vA3, kvA,
                          qa, qb, acc0, acc1, z);
            if (e + 4 < deg)
                edge_compute4(lane, grp, eiB, deg, vB0, vB1, vB2, vB3, kvB,
                              qa, qb, acc0, acc1, z);
        }
    } else {
        edge_loop_big(lane, sub, grp, deg, e0, col, qa, qb, k, v,
                      acc0, acc1, z);
    }

    const float rz = (z > 0.f) ? 1.f / z : 0.f;   // deg==0 / underflow -> 0
    acc0 *= rz;
    acc1 *= rz;

    // ---- write y fp16 (permuted space, features 2*lane, 2*lane+1) ----
    __half2 o;
    o.x = __float2half(acc0);
    o.y = __float2half(acc1);
    ((__half2*)y)[(size_t)node * 64 + lane] = o;
}

// ---------------------------------------------------------------------------
extern "C" void kernel_launch(void* const* d_in, const int* in_sizes, int n_in,
                              void* d_out, int out_size, void* d_ws, size_t ws_size,
                              hipStream_t stream)
{
    const float* x   = (const float*)d_in[0];
    const int*   row = (const int*)  d_in[1];
    const int*   col = (const int*)  d_in[2];
    const float* Wq  = (const float*)d_in[3];
    const float* bq  = (const float*)d_in[4];
    const float* Wk  = (const float*)d_in[5];
    const float* bk  = (const float*)d_in[6];
    const float* Wv  = (const float*)d_in[7];
    const float* bv  = (const float*)d_in[8];
    const float* Wo  = (const float*)d_in[9];
    const float* bo  = (const float*)d_in[10];
    float* out = (float*)d_out;

    const int n = in_sizes[0] / D;   // 100000
    const int e = in_sizes[1];       // 800000
    const size_t ND = (size_t)n * D;

    // Workspace (halves as unit):
    //   [0,   ND)   q  fp16 (permuted feature space)
    //   [ND,  2ND)  kh fp16 (permuted)
    //   [2ND, 3ND)  vh fp16 (permuted)
    //   [3ND, 4ND)  y  fp16 (permuted)
    //   then wh, wl (4*D*D shorts each), row_start
    __half* hb = (__half*)d_ws;
    __half* qh = hb;
    __half* kh = hb + ND;
    __half* vh = hb + 2 * ND;
    __half* y  = hb + 3 * ND;
    unsigned short* wh = (unsigned short*)(hb + 4 * ND);
    unsigned short* wl = wh + 4 * D * D;
    int* row_start = (int*)(wl + 4 * D * D);

    const int gx = (n + RT - 1) / RT;    // 1563

    convert_w<<<(D * D + 255) / 256, 256, 0, stream>>>(Wq, Wk, Wv, Wo, wh, wl);

    // hoisted: only depends on row; removes serial bubble before edge_attn
    build_row_start<<<(n + 1 + 255) / 256, 256, 0, stream>>>(row, row_start, n, e);

    // fused QKV from fp32 x, persistent pipelined, sel = bid%3.
    // ALL outputs fp16 now (halfmask=7); q gets scale 0.5 inside the
    // half-store path.
    gemm_pipe<<<510, 512, 0, stream>>>(
        x, wh, wl, bq, bk, bv,
        (void*)qh, (void*)kh, (void*)vh, 0.5f, n, 0, /*halfmask=*/7, /*permBias=*/1,
        /*nsel=*/3, gx, /*aHalf=*/0);

    edge_attn<<<(n + WPB - 1) / WPB, WPB * 64, 0, stream>>>(
        row_start, qh, kh, vh, col, y, n);

    // output projection from fp16 y, persistent pipelined (512 = all resident)
    gemm_pipe<<<512, 512, 0, stream>>>(
        y, wh, wl, bo, bo, bo,
        (void*)out, (void*)out, (void*)out, 1.0f, n, 3, /*halfmask=*/0, /*permBias=*/0,
        /*nsel=*/1, gx, /*aHalf=*/1);
}